// Round 1
// 87.319 us; speedup vs baseline: 1.0139x; 1.0139x over previous
//
#include <hip/hip_runtime.h>
#include <hip/hip_bf16.h>
#include <math.h>

// out = squash(ConvTranspose2d(x)+bias); routing loop is identity (R0 analysis).
// GEMM per parity class (ph,pw): out[px,co] = bias + sum_{tap in class} X·W_tap
// bf16 MFMA 16x16x32. Class taps: (0,0)->1, (0,1)/(1,0)->2, (1,1)->4.
//
// R11: OPERAND SWAP — mfma(w_frag, x_frag, acc) instead of (x, w). A/B frag
// lane layouts are identical on gfx950, so the swap is free, but the C/D
// layout transposes: lane n16 = output pixel, quad*4+r = d (capsule dim).
// Epilogue then does squash's sum(d) as 4 local FMAs + 2 shfl_xor butterfly
// steps (was 4 dependent DPP stages x 32 elements) and stores ONE float4
// nontemporal store per (row,tt) (was 32 scattered 4-B stores/thread).
// Staging (global_load_lds w=16), main loop, LDS layout frozen from R10.
//
// ws: [0,4.46MB) xbf bf16 [16][8][33][33][16]  (pad row/col 32 = zeros)
//     [4.5MB,..) Wl  bf16 [9][4][8][64][8] (tap,s,t,lane,j);
//                B[n=lane&15][k=quad*8+j], co=t*16+n, ci=s*32+quad*8+j.

typedef __attribute__((ext_vector_type(8))) __bf16 bf16x8;
typedef __attribute__((ext_vector_type(4))) float f32x4;

#define XPAD_ELEMS (16 * 8 * 33 * 33 * 16)   // 2230272
#define XPAD_B 139392
#define XPAD_MI 17424
#define XPAD_IH 528

__global__ __launch_bounds__(256) void prep(const float* __restrict__ x,
                                            const float* __restrict__ w,
                                            __hip_bfloat16* __restrict__ xbf,
                                            __hip_bfloat16* __restrict__ wl) {
    const int bx = blockIdx.x;
    if (bx < 1089) {  // padded x -> bf16, 8 elems/thread (2230272 = 1089*256*8)
        const int i  = (bx * 256 + threadIdx.x) * 8;
        const int b  = i / XPAD_B;
        const int r1 = i - b * XPAD_B;
        const int mi = r1 / XPAD_MI;
        const int r2 = r1 - mi * XPAD_MI;
        const int ih = r2 / XPAD_IH;
        const int r3 = r2 - ih * XPAD_IH;
        const int iw = r3 >> 4;
        const int di = r3 & 15;   // multiple of 8
        bf16x8 o = {};
        if (ih < 32 && iw < 32) {
            const float* s = x + b * 131072 + mi * 16384 + ih * 512 + iw * 16 + di;
            float4 a = *(const float4*)s;
            float4 c = *(const float4*)(s + 4);
            union { bf16x8 v; __hip_bfloat162 h[4]; } u;
            u.h[0] = __float22bfloat162_rn(make_float2(a.x, a.y));
            u.h[1] = __float22bfloat162_rn(make_float2(a.z, a.w));
            u.h[2] = __float22bfloat162_rn(make_float2(c.x, c.y));
            u.h[3] = __float22bfloat162_rn(make_float2(c.z, c.w));
            o = u.v;
        }
        *(bf16x8*)(xbf + i) = o;
    } else {          // w -> fragment-linear bf16
        const int idx = (bx - 1089) * 256 + threadIdx.x;  // = ci*1152+co*9+tap
        const int ci  = idx / 1152;
        const int rem = idx - ci * 1152;
        const int co  = rem / 9;
        const int tap = rem - co * 9;
        const int s = ci >> 5, quad = (ci >> 3) & 3, j = ci & 7;
        const int t = co >> 4, n16 = co & 15;
        const int dst = ((((tap * 4 + s) * 8 + t) * 64) + quad * 16 + n16) * 8 + j;
        wl[dst] = __float2bfloat16(w[idx]);
    }
}

// squash factor via HW approx rcp/rsq (threshold headroom 4.5x).
__device__ __forceinline__ float squash_f(float s2) {
    return s2 * __builtin_amdgcn_rsqf(s2 + 1e-7f) * __builtin_amdgcn_rcpf(1.f + s2);
}

// 16B-per-lane direct global->LDS copy (wave-uniform LDS base + lane*16).
__device__ __forceinline__ void g2l16(const __hip_bfloat16* g, __hip_bfloat16* l) {
    __builtin_amdgcn_global_load_lds(
        (const __attribute__((address_space(1))) unsigned int*)g,
        (__attribute__((address_space(3))) unsigned int*)l,
        16, 0, 0);
}

template <int PH, int PW, int NT>
__device__ __forceinline__ void caps_body(
    const __hip_bfloat16* __restrict__ xbf, const __hip_bfloat16* __restrict__ wl,
    const float* __restrict__ bias, float* __restrict__ out,
    __hip_bfloat16* bsh, int t0)
{
    constexpr int NH = PH ? 2 : 1, NW = PW ? 2 : 1;
    constexpr int NTAP = NH * NW;
    constexpr int CHE  = NT * 512;             // elems per (tap,s) chunk
    constexpr int STG  = NTAP * 4 * CHE;       // staged elems (<= 16384)
    const int tid = threadIdx.x, lane = tid & 63, wv = tid >> 6;
    const int q = blockIdx.y, b = blockIdx.z;

    // ---- stage B slice into LDS via direct DMA ----
    #pragma unroll
    for (int it = 0; it < STG / 2048; ++it) {
        const int ib      = it * 2048 + wv * 512;   // wave-uniform
        const int c2      = ib / CHE;               // ti*4 + s (wave-uniform)
        const int within  = ib % CHE;
        const int s  = c2 & 3, ti = c2 >> 2;
        const int kh = PH ? (ti / NW) * 2 : 1;
        const int kw = PW ? (ti % NW) * 2 : 1;
        const int tap = kh * 3 + kw;
        g2l16(wl + ((tap * 4 + s) * 8 + t0) * 512 + within + lane * 8,
              bsh + ib);
    }
    __syncthreads();

    const int rp = wv >> 1, chf = wv & 1;
    const int rw0 = q * 4 + rp * 2;        // class rows rw0, rw0+1 (oh = 2*rw+PH)
    const int n16  = lane & 15;
    const int quad = lane >> 4;
    const int c    = chf * 16 + n16;       // class col (ow = 2*c + PW)

    // x-frag (now the MFMA *B* operand): B[n=n16 -> pixel][k=quad*8+j]
    //   = xbf[b, 2s+(quad>>1), ih, iw, (quad&1)*8+j]
    const __hip_bfloat16* xq = xbf + b * XPAD_B + (quad >> 1) * XPAD_MI + (quad & 1) * 8;

    f32x4 acc[2][NT];
    #pragma unroll
    for (int r = 0; r < 2; ++r)
        #pragma unroll
        for (int tt = 0; tt < NT; ++tt) acc[r][tt] = (f32x4){0.f, 0.f, 0.f, 0.f};

    #pragma unroll
    for (int khi = 0; khi < NH; ++khi) {
        const int dh  = PH ? (1 - khi) : 0;
        const int ih0 = rw0 + dh;              // <= 32 (padded, zero rows)
        #pragma unroll
        for (int kwi = 0; kwi < NW; ++kwi) {
            const int dw = PW ? (1 - kwi) : 0;
            const int iw = c + dw;             // <= 32 (padded, zero col)
            const int ti = khi * NW + kwi;
            const __hip_bfloat16* ap = xq + ih0 * XPAD_IH + iw * 16;
            const __hip_bfloat16* wb = bsh + ti * (4 * CHE) + lane * 8;
            // hoist A for all 4 s (unconditional — padding handles edges)
            bf16x8 a0[4], a1[4];
            #pragma unroll
            for (int s = 0; s < 4; ++s) {
                a0[s] = *(const bf16x8*)(ap + s * (2 * XPAD_MI));
                a1[s] = *(const bf16x8*)(ap + s * (2 * XPAD_MI) + XPAD_IH);
            }
            #pragma unroll
            for (int tt = 0; tt < NT; ++tt) {
                #pragma unroll
                for (int s = 0; s < 4; ++s) {
                    bf16x8 bf = *(const bf16x8*)(wb + s * CHE + tt * 512);
                    // SWAPPED: w is the A operand, x is the B operand.
                    // D[m=co(tile-local)=quad*4+r][n=pixel=n16]
                    acc[0][tt] = __builtin_amdgcn_mfma_f32_16x16x32_bf16(bf, a0[s], acc[0][tt], 0, 0, 0);
                    acc[1][tt] = __builtin_amdgcn_mfma_f32_16x16x32_bf16(bf, a1[s], acc[1][tt], 0, 0, 0);
                }
            }
        }
    }

    // Epilogue: lane n16 = pixel col, quad*4+r = d. +bias (float4), squash via
    // 4 local FMAs + xor16/xor32 butterfly, ONE float4 nontemporal store each.
    const int ow = c * 2 + PW;
    float* ob = out + (size_t)(b * 8 + t0) * 65536 + ow * 16 + quad * 4;
    #pragma unroll
    for (int tt = 0; tt < NT; ++tt) {
        const f32x4 b4 = *(const f32x4*)(bias + (t0 + tt) * 16 + quad * 4);
        #pragma unroll
        for (int row = 0; row < 2; ++row) {
            const int oh = (rw0 + row) * 2 + PH;
            const float y0 = acc[row][tt][0] + b4[0];
            const float y1 = acc[row][tt][1] + b4[1];
            const float y2 = acc[row][tt][2] + b4[2];
            const float y3 = acc[row][tt][3] + b4[3];
            float s2 = fmaf(y0, y0, fmaf(y1, y1, fmaf(y2, y2, y3 * y3)));
            s2 += __shfl_xor(s2, 16);   // combine quad^1
            s2 += __shfl_xor(s2, 32);   // combine quad^2
            const float f = squash_f(s2);
            f32x4 v; v[0] = y0 * f; v[1] = y1 * f; v[2] = y2 * f; v[3] = y3 * f;
            __builtin_nontemporal_store(v, (f32x4*)(ob + tt * 65536 + oh * 1024));
        }
    }
}

__global__ __launch_bounds__(256, 5) void caps_mfma(
    const __hip_bfloat16* __restrict__ xbf, const __hip_bfloat16* __restrict__ wl,
    const float* __restrict__ bias, float* __restrict__ out)
{
    __shared__ __hip_bfloat16 bsh[16384];  // 32 KB * 5 blocks = 160 KB/CU exact
    const int bx = blockIdx.x;             // 10 variants, NT <= 4
    if      (bx <  2) caps_body<0, 0, 4>(xbf, wl, bias, out, bsh, bx * 4);
    else if (bx <  4) caps_body<0, 1, 4>(xbf, wl, bias, out, bsh, (bx - 2) * 4);
    else if (bx <  6) caps_body<1, 0, 4>(xbf, wl, bias, out, bsh, (bx - 4) * 4);
    else              caps_body<1, 1, 2>(xbf, wl, bias, out, bsh, (bx - 6) * 2);
}

extern "C" void kernel_launch(void* const* d_in, const int* in_sizes, int n_in,
                              void* d_out, int out_size, void* d_ws, size_t ws_size,
                              hipStream_t stream) {
    const float* x    = (const float*)d_in[0];
    const float* wgt  = (const float*)d_in[1];
    const float* bias = (const float*)d_in[2];
    float* out = (float*)d_out;

    __hip_bfloat16* xbf = (__hip_bfloat16*)d_ws;
    __hip_bfloat16* wlb = xbf + XPAD_ELEMS;

    prep<<<1089 + 576, 256, 0, stream>>>(x, wgt, xbf, wlb);
    caps_mfma<<<dim3(10, 8, 16), 256, 0, stream>>>(xbf, wlb, bias, out);
}